// Round 1
// 235.512 us; speedup vs baseline: 1.0554x; 1.0554x over previous
//
#include <hip/hip_runtime.h>
#include <hip/hip_bf16.h>

// DifferentiableXGB: logits = epilogue(x @ W1^T + b1)
//   split[b,n] = sum_d x[b,d]*W1[n,d] + b1[n]          (n = t*4+k, N=400)
//   S[b,t] = sum_k split[b,t,k]
//   logits[b,j] = sum_t fw[t]*S[b,t]*sum_k sigmoid(split[b,t,k])*fc_w[j,k] + fc_b[j]
//
// V8 = V7 with the hot path fully FLATTENED: no lambdas, no aggregates.
// R7 theory: WRITE_SIZE 50,816 KB / 163,840 threads = 317.6 B/thread ==
// sizeof(acc[4][5]) (320 B). The accumulator aggregate (held behind [&]
// lambda captures) was demoted to scratch -> every MFMA C-operand was a
// dependent L2/HBM round-trip (VGPR_Count=84, MfmaUtil 9.8%). V8 names
// every hot value individually (acc00..acc34, afr0..3, bfr0..4,
// areg00..areg11, bsrc0..4) and expands all inner loops via macros so
// every access is a compile-time-named register. Schedule/tiling/swizzle
// identical to V7:
//   - BM=128 x BN=400, BK=64, 640 threads (2 mh x 5 nf waves), 256 blocks.
//   - LDS double-buffer, ONE barrier per chunk; c+1 staging overlaps
//     compute(c).
//   - XOR-rotate swizzle phys_sub=(sub+row)&7 -> 0 bank conflicts.
//   - A staged fused from fp32 x (read once from HBM, cvt in regs).
//   - B (W1 bf16 in ws) via global_load_lds dwordx4.

typedef __bf16 bf16x8 __attribute__((ext_vector_type(8)));
typedef float f32x4 __attribute__((ext_vector_type(4)));

#define B_ROWS 32768
#define D_DIM  1024
#define N_COLS 400
#define BM     128
#define BK     64
#define NCHUNK 16          // 1024 / 64
#define THREADS 640        // 10 waves: mh = wave/5 (2), nf = wave%5 (5)
#define NTPW 5             // n-tiles (16 wide) per wave
#define MT   4             // m-tiles (16 tall) per wave (64 rows per mh)

__device__ __forceinline__ unsigned short f2bf(float f) {
    unsigned int u = __float_as_uint(f);
    u += 0x7FFFu + ((u >> 16) & 1u);   // RTNE
    return (unsigned short)(u >> 16);
}
__device__ __forceinline__ unsigned int pk2(float a, float b) {
    return (unsigned int)f2bf(a) | ((unsigned int)f2bf(b) << 16);
}
__device__ __forceinline__ uint4 cvt8u(float4 a, float4 b) {
    uint4 u;
    u.x = pk2(a.x, a.y); u.y = pk2(a.z, a.w);
    u.z = pk2(b.x, b.y); u.w = pk2(b.z, b.w);
    return u;
}
__device__ __forceinline__ bf16x8 cvt8(float4 a, float4 b) {
    return __builtin_bit_cast(bf16x8, cvt8u(a, b));
}

// tiny: W1 fp32 -> bf16 (1.6 MB)
__global__ void cvt_f32_bf16_kernel(const float* __restrict__ in,
                                    unsigned short* __restrict__ out) {
    size_t i = ((size_t)blockIdx.x * 256 + threadIdx.x) * 8;
    float4 v0 = *reinterpret_cast<const float4*>(in + i);
    float4 v1 = *reinterpret_cast<const float4*>(in + i + 4);
    *reinterpret_cast<uint4*>(out + i) = cvt8u(v0, v1);
}

// async 16B/lane global->LDS; lds dest = wave-uniform base + lane*16 (HW)
__device__ __forceinline__ void gl_lds16(const unsigned short* g,
                                         unsigned short* l) {
    __builtin_amdgcn_global_load_lds(
        (const __attribute__((address_space(1))) unsigned int*)g,
        (__attribute__((address_space(3))) unsigned int*)l,
        16, 0, 0);
}

// ---- macro machinery: every hot value is an individually named register ----
#define FOR_N_(OP, m) OP(m,0) OP(m,1) OP(m,2) OP(m,3) OP(m,4)
#define FOR_MN(OP) FOR_N_(OP,0) FOR_N_(OP,1) FOR_N_(OP,2) FOR_N_(OP,3)

#define DECL_ACC(m,n) f32x4 acc##m##n = {};
#define MFMA_MN(m,n) acc##m##n = __builtin_amdgcn_mfma_f32_16x16x32_bf16( \
        afr##m, bfr##n, acc##m##n, 0, 0, 0);

// MODE 0: A fp32 (fused cvt), B bf16 (ws). MODE 2: both fp32, plain loop.
template <int MODE>
__global__ __launch_bounds__(THREADS, 1) void xgb_v8(
    const float* __restrict__ x,
    const void*  __restrict__ b_any,
    const float* __restrict__ b1,
    const float* __restrict__ fw,
    const float* __restrict__ fcw,      // [2,4]
    const float* __restrict__ fcb,      // [2]
    float* __restrict__ out)            // [B,2]
{
    // double-buffered tiles; rows of 64 shorts, sub-chunk = 8 shorts (16 B),
    // swizzle: phys_sub = (sub + row) & 7
    __shared__ __align__(16) unsigned short Abuf[2][BM * BK];       // 32 KB
    __shared__ __align__(16) unsigned short Bbuf[2][N_COLS * BK];   // 100 KB
    __shared__ float Pbuf[BM * NTPW * 2];                           // 5 KB

    const int tid  = threadIdx.x;
    const int wave = tid >> 6;
    const int lane = tid & 63;
    const int quad = lane >> 4;
    const int l15  = lane & 15;
    const int mh   = wave / 5;          // 0..1  (m half: 64 rows)
    const int nf   = wave % 5;          // 0..4  (n fifth: 5 tiles)
    const int row0 = blockIdx.x * BM;

    FOR_MN(DECL_ACC)                    // acc00..acc34, 20 x f32x4

    if (MODE == 0) {
        const unsigned short* w1b = (const unsigned short*)b_any;

        // ---- B staging: 50 dma instrs, 5 per wave. stage s covers rows
        // 8s..8s+7. lane i -> row 8s+(i>>3); it fetches the logical sub
        // that belongs at phys slot i&7:  sub = ((i&7) - row) & 7.
#define BDECL(t) const unsigned short* bsrc##t; int bdst##t; \
        { const int s_ = wave + 10 * (t); const int rr_ = lane >> 3; \
          const int cc_ = ((lane & 7) - rr_) & 7; \
          bsrc##t = w1b + (size_t)(s_ * 8 + rr_) * D_DIM + cc_ * 8; \
          bdst##t = s_ * 512; }
        BDECL(0) BDECL(1) BDECL(2) BDECL(3) BDECL(4)

        // ---- A staging: 1024 sub-chunks (128 rows x 8 subs). STATIC map:
        // slot0 = tid (all threads), slot1 = tid+640 (tid<384: waves 0..5,
        // wave-uniform guard, compile-time indices -> register-resident).
        const int r0a = tid >> 3,          c0a = tid & 7;
        const int r1a = (tid + 640) >> 3,  c1a = (tid + 640) & 7;
        const bool hasU1 = (tid < 384);
        const float* asrc0 = x + (size_t)(row0 + r0a) * D_DIM + c0a * 8;
        const float* asrc1 = x + (size_t)(row0 + r1a) * D_DIM + c1a * 8;
        const int adst0 = r0a * 64 + ((c0a + r0a) & 7) * 8;   // swizzled
        const int adst1 = r1a * 64 + ((c1a + r1a) & 7) * 8;
        float4 areg00, areg01, areg10, areg11;

#define LOADA(kc) do { \
        areg00 = *reinterpret_cast<const float4*>(asrc0 + (kc));     \
        areg01 = *reinterpret_cast<const float4*>(asrc0 + (kc) + 4); \
        if (hasU1) { \
            areg10 = *reinterpret_cast<const float4*>(asrc1 + (kc));     \
            areg11 = *reinterpret_cast<const float4*>(asrc1 + (kc) + 4); \
        } } while (0)

#define WRITEA(Ab) do { \
        *reinterpret_cast<uint4*>((Ab) + adst0) = cvt8u(areg00, areg01); \
        if (hasU1) \
            *reinterpret_cast<uint4*>((Ab) + adst1) = cvt8u(areg10, areg11); \
        } while (0)

#define STAGEB(kc, Bb) do { \
        gl_lds16(bsrc0 + (kc), (Bb) + bdst0); \
        gl_lds16(bsrc1 + (kc), (Bb) + bdst1); \
        gl_lds16(bsrc2 + (kc), (Bb) + bdst2); \
        gl_lds16(bsrc3 + (kc), (Bb) + bdst3); \
        gl_lds16(bsrc4 + (kc), (Bb) + bdst4); } while (0)

#define LOAD_AFR(m) { const int row_ = mh * 64 + (m) * 16 + l15; \
        const int p_ = (quad + h * 4 + row_) & 7; \
        afr##m = *reinterpret_cast<const bf16x8*>(Ab_ + row_ * 64 + p_ * 8); }
#define LOAD_BFR(n) { const int row_ = (nf * NTPW + (n)) * 16 + l15; \
        const int p_ = (quad + h * 4 + row_) & 7; \
        bfr##n = *reinterpret_cast<const bf16x8*>(Bb_ + row_ * 64 + p_ * 8); }

        // prologue: stage chunk 0 into buffer 0
        LOADA(0);
        STAGEB(0, Bbuf[0]);
        WRITEA(Abuf[0]);

        #pragma unroll 1
        for (int c = 0; c < NCHUNK; ++c) {
            const int cur = c & 1;
            const unsigned short* Ab_ = Abuf[cur];
            const unsigned short* Bb_ = Bbuf[cur];
            __syncthreads();            // drains chunk-c staging; buf^1 free
            if (c + 1 < NCHUNK) {
                LOADA((c + 1) * BK);                 // globals fly over compute
                STAGEB((c + 1) * BK, Bbuf[1 - cur]); // dma flies over compute
            }
            #pragma unroll
            for (int h = 0; h < 2; ++h) {
                bf16x8 afr0, afr1, afr2, afr3;
                bf16x8 bfr0, bfr1, bfr2, bfr3, bfr4;
                LOAD_AFR(0) LOAD_AFR(1) LOAD_AFR(2) LOAD_AFR(3)
                LOAD_BFR(0) LOAD_BFR(1) LOAD_BFR(2) LOAD_BFR(3) LOAD_BFR(4)
                FOR_MN(MFMA_MN)
            }
            if (c + 1 < NCHUNK) WRITEA(Abuf[1 - cur]);  // cvt after compute
        }
    } else {
        // fallback: both fp32, plain loop (correctness insurance, no ws)
        const float* af = x + (size_t)(row0 + mh * 64 + l15) * D_DIM + quad * 8;
        const float* bf32 = (const float*)b_any
                          + (size_t)((nf * NTPW) * 16 + l15) * D_DIM + quad * 8;
        for (int step = 0; step < 32; ++step) {
            const int off = step * 32;
            bf16x8 afr0, afr1, afr2, afr3;
            bf16x8 bfr0, bfr1, bfr2, bfr3, bfr4;
#define LOAD_AFR2(m) { \
            float4 a0_ = *reinterpret_cast<const float4*>(af + (size_t)(m) * 16 * D_DIM + off); \
            float4 a1_ = *reinterpret_cast<const float4*>(af + (size_t)(m) * 16 * D_DIM + off + 4); \
            afr##m = cvt8(a0_, a1_); }
#define LOAD_BFR2(n) { \
            float4 b0_ = *reinterpret_cast<const float4*>(bf32 + (size_t)(n) * 16 * D_DIM + off); \
            float4 b1_ = *reinterpret_cast<const float4*>(bf32 + (size_t)(n) * 16 * D_DIM + off + 4); \
            bfr##n = cvt8(b0_, b1_); }
            LOAD_AFR2(0) LOAD_AFR2(1) LOAD_AFR2(2) LOAD_AFR2(3)
            LOAD_BFR2(0) LOAD_BFR2(1) LOAD_BFR2(2) LOAD_BFR2(3) LOAD_BFR2(4)
            FOR_MN(MFMA_MN)
        }
    }

    // ---- epilogue ----
    // C/D layout: col = l15 (within tile), row = quad*4 + reg   [m89/m91]
    const float fcw0 = fcw[l15 & 3];        // fc_w[0][k], k = col&3
    const float fcw1 = fcw[4 + (l15 & 3)];  // fc_w[1][k]

#define PRE_N(n) \
    const float bias##n = b1[(nf * NTPW + (n)) * 16 + l15]; \
    const float tw##n   = fw[((nf * NTPW + (n)) * 16 + l15) >> 2];
    PRE_N(0) PRE_N(1) PRE_N(2) PRE_N(3) PRE_N(4)

    // per (m,r): q = sum over n of fw[t]*sigmoid(split)*S ; then 16-lane sum.
    // k-sum S: lanes ^1,^2 (l15 bits 0-1 are k within tree).
#define EPI_TERM(m,r,n) { \
        const float split_ = acc##m##n[r] + bias##n; \
        float s_ = split_; \
        s_ += __shfl_xor(s_, 1); \
        s_ += __shfl_xor(s_, 2); \
        const float leaf_ = 1.0f / (1.0f + __expf(-split_)); \
        const float val_ = tw##n * leaf_ * s_; \
        q0 += val_ * fcw0; q1 += val_ * fcw1; }

#define EPI_ONE(m,r) { \
        float q0 = 0.f, q1 = 0.f; \
        EPI_TERM(m,r,0) EPI_TERM(m,r,1) EPI_TERM(m,r,2) \
        EPI_TERM(m,r,3) EPI_TERM(m,r,4) \
        q0 += __shfl_xor(q0, 1); q0 += __shfl_xor(q0, 2); \
        q0 += __shfl_xor(q0, 4); q0 += __shfl_xor(q0, 8); \
        q1 += __shfl_xor(q1, 1); q1 += __shfl_xor(q1, 2); \
        q1 += __shfl_xor(q1, 4); q1 += __shfl_xor(q1, 8); \
        const int row_ = mh * 64 + (m) * 16 + quad * 4 + (r); \
        if (l15 == 0) Pbuf[(row_ * NTPW + nf) * 2 + 0] = q0; \
        if (l15 == 1) Pbuf[(row_ * NTPW + nf) * 2 + 1] = q1; }

#define EPI_M(m) EPI_ONE(m,0) EPI_ONE(m,1) EPI_ONE(m,2) EPI_ONE(m,3)
    EPI_M(0) EPI_M(1) EPI_M(2) EPI_M(3)

    __syncthreads();

    if (tid < 2 * BM) {
        const int r = tid >> 1, j = tid & 1;
        float s = fcb[j];
        #pragma unroll
        for (int w = 0; w < NTPW; ++w)
            s += Pbuf[(r * NTPW + w) * 2 + j];
        out[(row0 + r) * 2 + j] = s;
    }
}

extern "C" void kernel_launch(void* const* d_in, const int* in_sizes, int n_in,
                              void* d_out, int out_size, void* d_ws, size_t ws_size,
                              hipStream_t stream) {
    const float* x   = (const float*)d_in[0];
    const float* W1  = (const float*)d_in[1];
    const float* b1  = (const float*)d_in[2];
    const float* fw  = (const float*)d_in[3];
    const float* fcw = (const float*)d_in[4];
    const float* fcb = (const float*)d_in[5];
    float* out = (float*)d_out;

    const size_t w1_elems = (size_t)N_COLS * D_DIM;   // 409,600
    if (ws_size >= w1_elems * sizeof(unsigned short)) {
        unsigned short* w1b = (unsigned short*)d_ws;
        cvt_f32_bf16_kernel<<<(int)(w1_elems / 2048), 256, 0, stream>>>(W1, w1b);
        xgb_v8<0><<<B_ROWS / BM, THREADS, 0, stream>>>(
            x, (const void*)w1b, b1, fw, fcw, fcb, out);
    } else {
        xgb_v8<2><<<B_ROWS / BM, THREADS, 0, stream>>>(
            x, (const void*)W1, b1, fw, fcw, fcb, out);
    }
}